// Round 10
// baseline (213.412 us; speedup 1.0000x reference)
//
#include <hip/hip_runtime.h>
#include <hip/hip_bf16.h>
#include <math.h>

#define D_MODEL 1024
#define BATCH   2
#define SEQ     2048
#define NHEAD   16
#define EHEAD   64
#define BS_ROWS (BATCH*SEQ)   // 4096

typedef unsigned short ushort_t;
typedef unsigned long long u64;
typedef __attribute__((ext_vector_type(8))) short short8;   // 8 bf16 = 4 VGPRs
typedef __attribute__((ext_vector_type(4))) float f32x4;    // MFMA C/D 16x16
typedef __attribute__((ext_vector_type(16))) float f32x16;  // MFMA C/D 32x32

union U4S8 { unsigned u[4]; short8 s; };

static __device__ __forceinline__ ushort_t f2bf(float x) {
  __hip_bfloat16 h = __float2bfloat16(x);
  return *reinterpret_cast<ushort_t*>(&h);
}
static __device__ __forceinline__ unsigned pk2(float a, float b) {
  __hip_bfloat162 t = __float22bfloat162_rn(make_float2(a, b));
  return *reinterpret_cast<unsigned*>(&t);
}
static __device__ __forceinline__ float bf2f(ushort_t u) {
  unsigned x = (unsigned)u << 16;
  return *reinterpret_cast<float*>(&x);
}

// async global->LDS, 16B/lane; LDS dest = wave-uniform base + lane*16
static __device__ __forceinline__ void gl16(const void* g, void* l) {
  __builtin_amdgcn_global_load_lds(
      (const __attribute__((address_space(1))) void*)g,
      (__attribute__((address_space(3))) void*)l, 16, 0, 0);
}

// ---------------------------------------------------------------------------
// Merged prep [validated R10-R15]: z<5 plain fp32->bf16 (E, WO,
// HQ*0.125*log2e, HK, HV); z 5..7 transposing cvt (WQ^T/WK^T/WV^T).
// ---------------------------------------------------------------------------
struct CvtAll {
  const float* src[8];
  ushort_t*    dst[8];
  int          n[8];
  float        scale[8];
};

__global__ __launch_bounds__(256) void cvt_all(CvtAll a) {
  const int z = blockIdx.y;
  if (z < 5) {
    const float4* __restrict__ s = (const float4*)a.src[z];
    ushort_t* __restrict__ d = a.dst[z];
    const float sc = a.scale[z];
    const int n4 = a.n[z] >> 2;
    for (int i = blockIdx.x * blockDim.x + threadIdx.x; i < n4;
         i += gridDim.x * blockDim.x) {
      float4 v = s[i];
      u64 pk = (u64)pk2(v.x * sc, v.y * sc) |
               ((u64)pk2(v.z * sc, v.w * sc) << 32);
      *(u64*)&d[i * 4] = pk;
    }
  } else {
    __shared__ ushort_t T[64][72];
    const float* __restrict__ s = a.src[z];
    ushort_t* __restrict__ d = a.dst[z];
    const int bi = (blockIdx.x >> 4) * 64;   // source row block
    const int bj = (blockIdx.x & 15) * 64;   // source col block
    const int r = threadIdx.x >> 2;
    const int c = (threadIdx.x & 3) * 16;
    const float* sp = s + (size_t)(bi + r) * D_MODEL + bj + c;
    #pragma unroll
    for (int u = 0; u < 4; u++) {
      float4 v = *(const float4*)(sp + u * 4);
      T[c + u*4 + 0][r] = f2bf(v.x);
      T[c + u*4 + 1][r] = f2bf(v.y);
      T[c + u*4 + 2][r] = f2bf(v.z);
      T[c + u*4 + 3][r] = f2bf(v.w);
    }
    __syncthreads();
    ushort_t* dp = d + (size_t)(bj + r) * D_MODEL + bi + c;
    *(short8*)dp       = *(const short8*)&T[r][c];
    *(short8*)(dp + 8) = *(const short8*)&T[r][c + 8];
  }
}

struct MM3 {
  const ushort_t* a[3];
  const ushort_t* b[3];
  void*           c[3];
};

// ---------------------------------------------------------------------------
// 128x128 bf16 MFMA GEMM, BK=64 [validated R12-R15]. Used for qkv (768 blk,
// 3/CU: barrier drain hidden by inter-block overlap). z==2 computes
// vT = Weff_v . E^T directly (operand swap, R23). 2048 % 128 == 0 so
// blocks never straddle the batch boundary.
// ---------------------------------------------------------------------------
template<typename OutT>
__global__ __launch_bounds__(256)
void mm128_bt(MM3 pp, int lda, int ldb, int ldc, int K) {
  __shared__ ushort_t As[128 * 64];
  __shared__ ushort_t Bs[128 * 64];
  const int z = blockIdx.z;
  const ushort_t* __restrict__ A = pp.a[z];
  const ushort_t* __restrict__ B = pp.b[z];
  void* __restrict__ C = pp.c[z];

  const int tid  = threadIdx.x;
  const int lane = tid & 63;
  const int w    = tid >> 6;
  const int ww   = w >> 1, wc = w & 1;
  const int l15  = lane & 15, quad = lane >> 4;
  const bool swz2 = __is_same(OutT, ushort_t) && (z == 2);
  const int m0 = (swz2 ? blockIdx.y : blockIdx.x) * 128;
  const int n0 = (swz2 ? blockIdx.x : blockIdx.y) * 128;

  const ushort_t* gA[4];
  const ushort_t* gB[4];
  ushort_t* lA[4];
  ushort_t* lB[4];
  #pragma unroll
  for (int i = 0; i < 4; i++) {
    const int p  = w * 256 + i * 64 + lane;
    const int rw = p >> 3, cc = (p & 7) ^ (rw & 7);
    gA[i] = A + (size_t)(m0 + rw) * lda + cc * 8;
    gB[i] = B + (size_t)(n0 + rw) * ldb + cc * 8;
    lA[i] = &As[(w * 256 + i * 64) * 8];
    lB[i] = &Bs[(w * 256 + i * 64) * 8];
  }

  int iA[4][2], iB[4][2];
  #pragma unroll
  for (int mt = 0; mt < 4; mt++) {
    const int ra = ww * 64 + mt * 16 + l15;
    const int rb = wc * 64 + mt * 16 + l15;
    #pragma unroll
    for (int ks = 0; ks < 2; ks++) {
      iA[mt][ks] = (ra * 8 + ((ks * 4 + quad) ^ (ra & 7))) * 8;
      iB[mt][ks] = (rb * 8 + ((ks * 4 + quad) ^ (rb & 7))) * 8;
    }
  }

  f32x4 acc[4][4];
  #pragma unroll
  for (int i = 0; i < 4; i++)
    #pragma unroll
    for (int j = 0; j < 4; j++) acc[i][j] = (f32x4){0.f, 0.f, 0.f, 0.f};

  for (int k0 = 0; k0 < K; k0 += 64) {
    __syncthreads();
    #pragma unroll
    for (int i = 0; i < 4; i++) {
      gl16(gA[i] + k0, lA[i]);
      gl16(gB[i] + k0, lB[i]);
    }
    __syncthreads();

    #pragma unroll
    for (int ks = 0; ks < 2; ks++) {
      short8 af[4], bf[4];
      #pragma unroll
      for (int mt = 0; mt < 4; mt++) af[mt] = *(const short8*)&As[iA[mt][ks]];
      #pragma unroll
      for (int nt = 0; nt < 4; nt++) bf[nt] = *(const short8*)&Bs[iB[nt][ks]];
      #pragma unroll
      for (int mt = 0; mt < 4; mt++)
        #pragma unroll
        for (int nt = 0; nt < 4; nt++)
          acc[mt][nt] = __builtin_amdgcn_mfma_f32_16x16x32_bf16(
              af[mt], bf[nt], acc[mt][nt], 0, 0, 0);
    }
  }

  if constexpr (__is_same(OutT, ushort_t)) {
    if (z == 2) {
      // direct vT write: row=he, col=s (contiguous, coalesced)
      ushort_t* Cp = (ushort_t*)C + (size_t)(n0 >> 11) * D_MODEL * SEQ;
      const int c0 = (n0 & (SEQ - 1)) + wc * 64;
      #pragma unroll
      for (int mt = 0; mt < 4; mt++)
        #pragma unroll
        for (int nt = 0; nt < 4; nt++)
          #pragma unroll
          for (int r = 0; r < 4; r++) {
            const size_t row = (size_t)(m0 + ww * 64 + mt * 16 + quad * 4 + r);
            const int    col = c0 + nt * 16 + l15;
            Cp[row * SEQ + col] = f2bf(acc[mt][nt][r]);
          }
      return;
    }
  }

  #pragma unroll
  for (int mt = 0; mt < 4; mt++)
    #pragma unroll
    for (int nt = 0; nt < 4; nt++)
      #pragma unroll
      for (int r = 0; r < 4; r++) {
        const size_t row = (size_t)(m0 + ww * 64 + mt * 16 + quad * 4 + r);
        const int    col = n0 + wc * 64 + nt * 16 + l15;
        if constexpr (__is_same(OutT, float))
          ((float*)C)[row * ldc + col] = acc[mt][nt][r];
        else
          ((ushort_t*)C)[row * ldc + col] = f2bf(acc[mt][nt][r]);
      }
}

// ---------------------------------------------------------------------------
// R25: 128x64-tile BK=64 GEMM — the middle point between mm64 (1:1
// MFMA:ds_read, ~343TF class) and mm128 (2:1 but needs >=2 blocks/CU for
// barrier-drain overlap, R22). 4 waves in 2x2, each wave 64x32 (4x2 MFMA
// frags): 16 MFMA : 12 ds_read_b128 per K-step (1.33:1). LDS 24KB ->
// 6 blocks/CU cap. For out (M=4096,N=1024): grid 32x16 = 512 blk = 2/CU.
// A-staging = mm128's validated 4-chunk map; B-staging = mm64's validated
// 2-chunk map; frag reads = validated slot=c^(r&7).
// ---------------------------------------------------------------------------
template<typename OutT>
__global__ __launch_bounds__(256)
void mm12864_bt(MM3 pp, int lda, int ldb, int ldc, int K) {
  __shared__ ushort_t As[128 * 64];
  __shared__ ushort_t Bs[64 * 64];
  const int z = blockIdx.z;
  const ushort_t* __restrict__ A = pp.a[z];
  const ushort_t* __restrict__ B = pp.b[z];
  void* __restrict__ C = pp.c[z];

  const int tid  = threadIdx.x;
  const int lane = tid & 63;
  const int w    = tid >> 6;
  const int wm   = w >> 1, wn = w & 1;
  const int l15  = lane & 15, quad = lane >> 4;
  const int m0 = blockIdx.x * 128;
  const int n0 = blockIdx.y * 64;

  // A: 1024 chunks, 4/thread (mm128 pattern)
  const ushort_t* gA[4];
  ushort_t* lA[4];
  #pragma unroll
  for (int i = 0; i < 4; i++) {
    const int p  = w * 256 + i * 64 + lane;
    const int rw = p >> 3, cc = (p & 7) ^ (rw & 7);
    gA[i] = A + (size_t)(m0 + rw) * lda + cc * 8;
    lA[i] = &As[(w * 256 + i * 64) * 8];
  }
  // B: 512 chunks, 2/thread (mm64 pattern)
  const int p0 = tid, p1 = tid + 256;
  const int rw0 = p0 >> 3, cc0 = (p0 & 7) ^ (rw0 & 7);
  const int rw1 = p1 >> 3, cc1 = (p1 & 7) ^ (rw1 & 7);
  const ushort_t* gB0 = B + (size_t)(n0 + rw0) * ldb + cc0 * 8;
  const ushort_t* gB1 = B + (size_t)(n0 + rw1) * ldb + cc1 * 8;
  ushort_t* lB0 = &Bs[(w * 64) * 8];
  ushort_t* lB1 = &Bs[(256 + w * 64) * 8];

  int iA[4][2], iB[2][2];
  #pragma unroll
  for (int mt = 0; mt < 4; mt++) {
    const int ra = wm * 64 + mt * 16 + l15;
    #pragma unroll
    for (int ks = 0; ks < 2; ks++)
      iA[mt][ks] = (ra * 8 + ((ks * 4 + quad) ^ (ra & 7))) * 8;
  }
  #pragma unroll
  for (int nt = 0; nt < 2; nt++) {
    const int rb = wn * 32 + nt * 16 + l15;
    #pragma unroll
    for (int ks = 0; ks < 2; ks++)
      iB[nt][ks] = (rb * 8 + ((ks * 4 + quad) ^ (rb & 7))) * 8;
  }

  f32x4 acc[4][2];
  #pragma unroll
  for (int i = 0; i < 4; i++)
    #pragma unroll
    for (int j = 0; j < 2; j++) acc[i][j] = (f32x4){0.f, 0.f, 0.f, 0.f};

  for (int k0 = 0; k0 < K; k0 += 64) {
    __syncthreads();
    #pragma unroll
    for (int i = 0; i < 4; i++) gl16(gA[i] + k0, lA[i]);
    gl16(gB0 + k0, lB0);
    gl16(gB1 + k0, lB1);
    __syncthreads();

    #pragma unroll
    for (int ks = 0; ks < 2; ks++) {
      short8 af[4], bf[2];
      #pragma unroll
      for (int mt = 0; mt < 4; mt++) af[mt] = *(const short8*)&As[iA[mt][ks]];
      #pragma unroll
      for (int nt = 0; nt < 2; nt++) bf[nt] = *(const short8*)&Bs[iB[nt][ks]];
      #pragma unroll
      for (int mt = 0; mt < 4; mt++)
        #pragma unroll
        for (int nt = 0; nt < 2; nt++)
          acc[mt][nt] = __builtin_amdgcn_mfma_f32_16x16x32_bf16(
              af[mt], bf[nt], acc[mt][nt], 0, 0, 0);
    }
  }

  #pragma unroll
  for (int mt = 0; mt < 4; mt++)
    #pragma unroll
    for (int nt = 0; nt < 2; nt++)
      #pragma unroll
      for (int r = 0; r < 4; r++) {
        const size_t row = (size_t)(m0 + wm * 64 + mt * 16 + quad * 4 + r);
        const int    col = n0 + wn * 32 + nt * 16 + l15;
        if constexpr (__is_same(OutT, float))
          ((float*)C)[row * ldc + col] = acc[mt][nt][r];
        else
          ((ushort_t*)C)[row * ldc + col] = f2bf(acc[mt][nt][r]);
      }
}

// ---------------------------------------------------------------------------
// R16: 64x64-tile BK=64 GEMM. Kept for Weff (768 blk, 3/CU).
// ---------------------------------------------------------------------------
template<typename OutT>
__global__ __launch_bounds__(256)
void mm64_bt(MM3 pp, int lda, int ldb, int ldc, int K) {
  __shared__ ushort_t As[64 * 64];
  __shared__ ushort_t Bs[64 * 64];
  const int z = blockIdx.z;
  const ushort_t* __restrict__ A = pp.a[z];
  const ushort_t* __restrict__ B = pp.b[z];
  void* __restrict__ C = pp.c[z];

  const int tid  = threadIdx.x;
  const int lane = tid & 63;
  const int w    = tid >> 6;
  const int wm   = w >> 1, wn = w & 1;
  const int l15  = lane & 15, quad = lane >> 4;
  const int m0 = blockIdx.x * 64;
  const int n0 = blockIdx.y * 64;

  const int p0 = tid, p1 = tid + 256;
  const int rw0 = p0 >> 3, cc0 = (p0 & 7) ^ (rw0 & 7);
  const int rw1 = p1 >> 3, cc1 = (p1 & 7) ^ (rw1 & 7);
  const ushort_t* gA0 = A + (size_t)(m0 + rw0) * lda + cc0 * 8;
  const ushort_t* gA1 = A + (size_t)(m0 + rw1) * lda + cc1 * 8;
  const ushort_t* gB0 = B + (size_t)(n0 + rw0) * ldb + cc0 * 8;
  const ushort_t* gB1 = B + (size_t)(n0 + rw1) * ldb + cc1 * 8;
  ushort_t* lA0 = &As[(w * 64) * 8];         // chunks w*64+lane
  ushort_t* lA1 = &As[(256 + w * 64) * 8];
  ushort_t* lB0 = &Bs[(w * 64) * 8];
  ushort_t* lB1 = &Bs[(256 + w * 64) * 8];

  int iA[2][2], iB[2][2];
  #pragma unroll
  for (int mt = 0; mt < 2; mt++) {
    const int ra = wm * 32 + mt * 16 + l15;
    const int rb = wn * 32 + mt * 16 + l15;
    #pragma unroll
    for (int ks = 0; ks < 2; ks++) {
      iA[mt][ks] = (ra * 8 + ((ks * 4 + quad) ^ (ra & 7))) * 8;
      iB[mt][ks] = (rb * 8 + ((ks * 4 + quad) ^ (rb & 7))) * 8;
    }
  }

  f32x4 acc[2][2];
  #pragma unroll
  for (int i = 0; i < 2; i++)
    #pragma unroll
    for (int j = 0; j < 2; j++) acc[i][j] = (f32x4){0.f, 0.f, 0.f, 0.f};

  for (int k0 = 0; k0 < K; k0 += 64) {
    __syncthreads();
    gl16(gA0 + k0, lA0);
    gl16(gA1 + k0, lA1);
    gl16(gB0 + k0, lB0);
    gl16(gB1 + k0, lB1);
    __syncthreads();

    #pragma unroll
    for (int ks = 0; ks < 2; ks++) {
      short8 af[2], bf[2];
      #pragma unroll
      for (int mt = 0; mt < 2; mt++) af[mt] = *(const short8*)&As[iA[mt][ks]];
      #pragma unroll
      for (int nt = 0; nt < 2; nt++) bf[nt] = *(const short8*)&Bs[iB[nt][ks]];
      #pragma unroll
      for (int mt = 0; mt < 2; mt++)
        #pragma unroll
        for (int nt = 0; nt < 2; nt++)
          acc[mt][nt] = __builtin_amdgcn_mfma_f32_16x16x32_bf16(
              af[mt], bf[nt], acc[mt][nt], 0, 0, 0);
    }
  }

  #pragma unroll
  for (int mt = 0; mt < 2; mt++)
    #pragma unroll
    for (int nt = 0; nt < 2; nt++)
      #pragma unroll
      for (int r = 0; r < 4; r++) {
        const size_t row = (size_t)(m0 + wm * 32 + mt * 16 + quad * 4 + r);
        const int    col = n0 + wn * 32 + nt * 16 + l15;
        if constexpr (__is_same(OutT, float))
          ((float*)C)[row * ldc + col] = acc[mt][nt][r];
        else
          ((ushort_t*)C)[row * ldc + col] = f2bf(acc[mt][nt][r]);
      }
}

// ---------------------------------------------------------------------------
// MFMA flash attention — R24 kernel VERBATIM (NSPLIT=1, writes ocat
// directly; combine deleted — measured 213.0 total, the best config).
// R17-R21: flash is bound by per-CU issue throughput of the
// QK->exp2->pack->PV stream; NSPLIT=1 fixes total waves at 2048 (8/CU) so
// ~63 µs is its floor, paid for by deleting combine (~14 µs net win).
// ---------------------------------------------------------------------------
#define QBLK 128
#define NIT (SEQ / 64)   // 32

__global__ __launch_bounds__(256)
void flash_attn(const ushort_t* __restrict__ q, const ushort_t* __restrict__ k,
                const ushort_t* __restrict__ vT, ushort_t* __restrict__ ocat) {
  const int q0    = blockIdx.x * QBLK;
  const int bh    = blockIdx.y;
  const int b = bh >> 4, h = bh & 15;
  const size_t row0 = (size_t)b * SEQ;
  const int hc    = h * EHEAD;

  __shared__ ushort_t Ks[64 * 64];   // swizzled chunks of [key][e]
  __shared__ ushort_t Vs[64 * 64];   // swizzled chunks of [e][key]

  const int tid  = threadIdx.x;
  const int lane = tid & 63;
  const int w    = tid >> 6;
  const int l31  = lane & 31;
  const int hi   = lane >> 5;
  const int q7v  = l31 & 7;
  const int qw   = w * 32;           // wave's 32 q-rows

  // Q B-fragments (B[e][q]: col=q=l31, k=e=es*16+hi*8+j), from global.
  short8 bq[4];
  {
    const ushort_t* src =
        q + (row0 + q0 + qw + l31) * D_MODEL + hc + hi * 8;
    #pragma unroll
    for (int es = 0; es < 4; es++)
      bq[es] = *(const short8*)(src + es * 16);
  }

  f32x16 ot[2];   // O^T[e=et*32+...][q=l31]
  #pragma unroll
  for (int r = 0; r < 16; r++) { ot[0][r] = 0.f; ot[1][r] = 0.f; }
  float lsum = 0.f;

  // staging: validated 512-chunk map (p -> row p>>3, slot (p&7)^(row&7))
  const int p0 = tid, p1 = tid + 256;
  const int rw0 = p0 >> 3, cc0 = (p0 & 7) ^ (rw0 & 7);
  const int rw1 = p1 >> 3, cc1 = (p1 & 7) ^ (rw1 & 7);
  const ushort_t* kg0 = k + (row0 + rw0) * D_MODEL + hc + cc0 * 8;   // +kt*D
  const ushort_t* kg1 = k + (row0 + rw1) * D_MODEL + hc + cc1 * 8;
  const ushort_t* vg0 = vT + ((size_t)(b * D_MODEL + hc + rw0)) * SEQ + cc0 * 8;
  const ushort_t* vg1 = vT + ((size_t)(b * D_MODEL + hc + rw1)) * SEQ + cc1 * 8;

  // precomputed swizzled read slots
  int slotK[4];          // QK^T A-frag: e-chunk (es*2+hi) ^ q7v
  #pragma unroll
  for (int es = 0; es < 4; es++) slotK[es] = (((es * 2 + hi) ^ q7v)) * 8;
  int slotV[2][2];       // PV A-frag: key-chunk (mt*4+ks2*2+hi) ^ q7v
  #pragma unroll
  for (int mt = 0; mt < 2; mt++)
    #pragma unroll
    for (int ks2 = 0; ks2 < 2; ks2++)
      slotV[mt][ks2] = (((mt * 4 + ks2 * 2 + hi) ^ q7v)) * 8;

  short8 kr0, kr1, vr0, vr1;
  {
    kr0 = *(const short8*)(kg0);
    kr1 = *(const short8*)(kg1);
    vr0 = *(const short8*)(vg0);
    vr1 = *(const short8*)(vg1);
  }
  *(short8*)&Ks[p0 * 8] = kr0;
  *(short8*)&Ks[p1 * 8] = kr1;
  *(short8*)&Vs[p0 * 8] = vr0;
  *(short8*)&Vs[p1 * 8] = vr1;

  for (int it = 0; it < NIT; it++) {
    __syncthreads();   // staged LDS visible to all waves

    if (it + 1 < NIT) {
      const int kn = (it + 1) * 64;
      const size_t ko = (size_t)kn * D_MODEL;
      kr0 = *(const short8*)(kg0 + ko);
      kr1 = *(const short8*)(kg1 + ko);
      vr0 = *(const short8*)(vg0 + kn);
      vr1 = *(const short8*)(vg1 + kn);
    }

    #pragma unroll
    for (int mt = 0; mt < 2; mt++) {       // two 32-key chunks
      // --- S^T chunk = K . Q^T  (A: row=key=mt*32+l31, k=e slice)
      f32x16 st;
      #pragma unroll
      for (int r = 0; r < 16; r++) st[r] = 0.f;
      short8 af[4];
      #pragma unroll
      for (int es = 0; es < 4; es++)
        af[es] = *(const short8*)&Ks[(mt * 32 + l31) * 64 + slotK[es]];
      __builtin_amdgcn_s_setprio(1);
      #pragma unroll
      for (int es = 0; es < 4; es++)
        st = __builtin_amdgcn_mfma_f32_32x32x16_bf16(af[es], bq[es], st,
                                                     0, 0, 0);
      __builtin_amdgcn_s_setprio(0);

      // --- in-register softmax: exp2 (log2e pre-folded) + tree sums
      #pragma unroll
      for (int r = 0; r < 16; r++) st[r] = __builtin_amdgcn_exp2f(st[r]);
      lsum += (((st[0] + st[1]) + (st[2] + st[3])) +
               ((st[4] + st[5]) + (st[6] + st[7]))) +
              (((st[8] + st[9]) + (st[10] + st[11])) +
               ((st[12] + st[13]) + (st[14] + st[15])));

      // --- P^T B-frags: pk2 pairs + permlane32_swap (lane needs keys
      // hi*8..+7 of each 16-key slice; swap exchanges vdst.hi <-> vsrc.lo)
      unsigned a0 = pk2(st[0],  st[1]),  b0 = pk2(st[2],  st[3]);
      unsigned c0 = pk2(st[4],  st[5]),  d0 = pk2(st[6],  st[7]);
      unsigned a1 = pk2(st[8],  st[9]),  b1 = pk2(st[10], st[11]);
      unsigned c1 = pk2(st[12], st[13]), d1 = pk2(st[14], st[15]);
      asm volatile("v_permlane32_swap_b32 %0, %1" : "+v"(a0), "+v"(c0));
      asm volatile("v_permlane32_swap_b32 %0, %1" : "+v"(b0), "+v"(d0));
      asm volatile("v_permlane32_swap_b32 %0, %1" : "+v"(a1), "+v"(c1));
      asm volatile("v_permlane32_swap_b32 %0, %1" : "+v"(b1), "+v"(d1));
      short8 pb[2];
      { U4S8 u; u.u[0] = a0; u.u[1] = b0; u.u[2] = c0; u.u[3] = d0; pb[0] = u.s; }
      { U4S8 u; u.u[0] = a1; u.u[1] = b1; u.u[2] = c1; u.u[3] = d1; pb[1] = u.s; }

      // --- O^T += V^T . P^T  (A: row=e=et*32+l31, k=key slice)
      short8 av[2][2];
      #pragma unroll
      for (int et = 0; et < 2; et++)
        #pragma unroll
        for (int ks2 = 0; ks2 < 2; ks2++)
          av[et][ks2] =
              *(const short8*)&Vs[(et * 32 + l31) * 64 + slotV[mt][ks2]];
      __builtin_amdgcn_s_setprio(1);
      #pragma unroll
      for (int et = 0; et < 2; et++)
        #pragma unroll
        for (int ks2 = 0; ks2 < 2; ks2++)
          ot[et] = __builtin_amdgcn_mfma_f32_32x32x16_bf16(
              av[et][ks2], pb[ks2], ot[et], 0, 0, 0);
      __builtin_amdgcn_s_setprio(0);
    }

    __syncthreads();   // all waves done reading Ks/Vs
    if (it + 1 < NIT) {
      *(short8*)&Ks[p0 * 8] = kr0;
      *(short8*)&Ks[p1 * 8] = kr1;
      *(short8*)&Vs[p0 * 8] = vr0;
      *(short8*)&Vs[p1 * 8] = vr1;
    }
  }

  // --- epilogue: normalize and write FINAL output directly to ocat
  // (layout [b][s][h*EHEAD+e]; reg r=rq*4+j -> e = et*32 + 8*rq + 4*hi + j)
  {
    const float s = lsum + __shfl_xor(lsum, 32);
    const float inv = 1.f / s;
    const int qL = q0 + qw + l31;
    ushort_t* orow = ocat + ((size_t)(b * SEQ + qL)) * D_MODEL + hc;
    #pragma unroll
    for (int et = 0; et < 2; et++)
      #pragma unroll
      for (int rq = 0; rq < 4; rq++) {
        const int e0 = et * 32 + rq * 8 + hi * 4;
        u64 pk = (u64)pk2(ot[et][rq * 4 + 0] * inv, ot[et][rq * 4 + 1] * inv) |
                 ((u64)pk2(ot[et][rq * 4 + 2] * inv, ot[et][rq * 4 + 3] * inv)
                  << 32);
        *(u64*)&orow[e0] = pk;
      }
  }
}

// ---------------------------------------------------------------------------
// 5 dispatches:
//  0. cvt_all (E, WO, HQ*0.125*log2e, HK, HV plain; WQ/WK/WV transposed)
//  1. Weff_z = H_z @ W_z          (mm64: 768 blk, 3/CU)
//  2. qkv_z  = E @ Weff_z^T       (mm128, 768 blk; z=2 operand-swapped)
//  3. flash NSPLIT=1              (R24: 512 blk, writes ocat directly)
//  4. out = ocat @ WO^T (fp32)    (R25: mm12864, 512 blk = 2/CU)
// ws: 76.5 MB (R14 layout; Opart/lpart unused).
// ---------------------------------------------------------------------------
extern "C" void kernel_launch(void* const* d_in, const int* in_sizes, int n_in,
                              void* d_out, int out_size, void* d_ws, size_t ws_size,
                              hipStream_t stream) {
  const float* E  = (const float*)d_in[0];
  const float* WQ = (const float*)d_in[1];
  const float* WK = (const float*)d_in[2];
  const float* WV = (const float*)d_in[3];
  const float* WO = (const float*)d_in[4];
  const float* HQ = (const float*)d_in[5];
  const float* HK = (const float*)d_in[6];
  const float* HV = (const float*)d_in[7];
  float* out = (float*)d_out;

  const size_t NE = (size_t)BS_ROWS * D_MODEL;  // 4M
  const size_t NW = (size_t)D_MODEL * D_MODEL;  // 1M

  ushort_t* Ebf   = (ushort_t*)d_ws;            // 4M
  ushort_t* WOb   = Ebf + NE;                   // 1M
  ushort_t* Hb    = WOb + NW;                   // 3 x 1M
  ushort_t* Wt    = Hb + 3 * NW;                // 3 x 1M (W^T)
  ushort_t* Weff  = Wt + 3 * NW;                // 3 x 1M
  ushort_t* qb    = Weff + 3 * NW;              // 4M
  ushort_t* kb    = qb + NE;                    // 4M
  ushort_t* vTb   = kb + NE;                    // 4M ([b][he][s])
  ushort_t* ocat  = vTb + NE;                   // 4M

  // 0. merged conversions (HQ scale folds 1/sqrt(64) AND log2e)
  {
    CvtAll a;
    const float* s2[8] = {E, WO, HQ, HK, HV, WQ, WK, WV};
    ushort_t* dsts[8] = {Ebf, WOb, Hb, Hb + NW, Hb + 2 * NW,
                         Wt, Wt + NW, Wt + 2 * NW};
    for (int i = 0; i < 8; i++) {
      a.src[i] = s2[i]; a.dst[i] = dsts[i];
      a.n[i] = (i == 0) ? (int)NE : (int)NW;
      a.scale[i] = (i == 2) ? (0.125f * 1.44269504088896f) : 1.0f;
    }
    cvt_all<<<dim3(256, 8), 256, 0, stream>>>(a);
  }
  // 1. Weff_z = H_z @ W_z  (64-tile bt-GEMM against W^T; 768 blocks)
  {
    MM3 p;
    p.a[0] = Hb; p.a[1] = Hb + NW; p.a[2] = Hb + 2 * NW;
    p.b[0] = Wt; p.b[1] = Wt + NW; p.b[2] = Wt + 2 * NW;
    p.c[0] = Weff; p.c[1] = Weff + NW; p.c[2] = Weff + 2 * NW;
    mm64_bt<ushort_t><<<dim3(16, 16, 3), 256, 0, stream>>>(
        p, D_MODEL, D_MODEL, D_MODEL, D_MODEL);
  }
  // 2. qkv_z = E @ Weff_z^T  (z=2: A=Weff_v, B=Ebf -> vT direct)
  {
    MM3 p;
    p.a[0] = Ebf; p.a[1] = Ebf; p.a[2] = Weff + 2 * NW;
    p.b[0] = Weff; p.b[1] = Weff + NW; p.b[2] = Ebf;
    p.c[0] = qb; p.c[1] = kb; p.c[2] = vTb;
    mm128_bt<ushort_t><<<dim3(32, 8, 3), 256, 0, stream>>>(
        p, D_MODEL, D_MODEL, D_MODEL, D_MODEL);
  }
  // 3. flash NSPLIT=1 (16 x 32 = 512 blocks) -> ocat directly
  flash_attn<<<dim3(SEQ / QBLK, 32), 256, 0, stream>>>(qb, kb, vTb, ocat);
  // 4. out = ocat @ WO^T  (R25: 128x64-tile; 32 x 16 = 512 blocks, 2/CU)
  {
    MM3 p;
    p.a[0] = ocat; p.b[0] = WOb; p.c[0] = out;
    p.a[1] = ocat; p.b[1] = WOb; p.c[1] = out;
    p.a[2] = ocat; p.b[2] = WOb; p.c[2] = out;
    mm12864_bt<float><<<dim3(32, 16, 1), 256, 0, stream>>>(
        p, D_MODEL, D_MODEL, D_MODEL, D_MODEL);
  }
}

// Round 11
// 207.572 us; speedup vs baseline: 1.0281x; 1.0281x over previous
//
#include <hip/hip_runtime.h>
#include <hip/hip_bf16.h>
#include <math.h>

#define D_MODEL 1024
#define BATCH   2
#define SEQ     2048
#define NHEAD   16
#define EHEAD   64
#define BS_ROWS (BATCH*SEQ)   // 4096

typedef unsigned short ushort_t;
typedef unsigned long long u64;
typedef __attribute__((ext_vector_type(8))) short short8;   // 8 bf16 = 4 VGPRs
typedef __attribute__((ext_vector_type(4))) float f32x4;    // MFMA C/D 16x16
typedef __attribute__((ext_vector_type(16))) float f32x16;  // MFMA C/D 32x32

union U4S8 { unsigned u[4]; short8 s; };

static __device__ __forceinline__ ushort_t f2bf(float x) {
  __hip_bfloat16 h = __float2bfloat16(x);
  return *reinterpret_cast<ushort_t*>(&h);
}
static __device__ __forceinline__ unsigned pk2(float a, float b) {
  __hip_bfloat162 t = __float22bfloat162_rn(make_float2(a, b));
  return *reinterpret_cast<unsigned*>(&t);
}
static __device__ __forceinline__ float bf2f(ushort_t u) {
  unsigned x = (unsigned)u << 16;
  return *reinterpret_cast<float*>(&x);
}

// async global->LDS, 16B/lane; LDS dest = wave-uniform base + lane*16
static __device__ __forceinline__ void gl16(const void* g, void* l) {
  __builtin_amdgcn_global_load_lds(
      (const __attribute__((address_space(1))) void*)g,
      (__attribute__((address_space(3))) void*)l, 16, 0, 0);
}

// ---------------------------------------------------------------------------
// R26 cvt_pre: ONLY what Weff needs — z<3 plain fp32->bf16 of H
// (HQ*0.125*log2e, HK, HV); z 3..5 transposing cvt (WQ^T/WK^T/WV^T).
// E and WO conversion moved into the Weff dispatch (overlap, R26).
// ---------------------------------------------------------------------------
struct CvtPre {
  const float* src[6];
  ushort_t*    dst[6];
  float        scale[6];
};

__global__ __launch_bounds__(256) void cvt_pre(CvtPre a) {
  const int z = blockIdx.y;
  if (z < 3) {
    const float4* __restrict__ s = (const float4*)a.src[z];
    ushort_t* __restrict__ d = a.dst[z];
    const float sc = a.scale[z];
    const int n4 = (D_MODEL * D_MODEL) >> 2;
    for (int i = blockIdx.x * blockDim.x + threadIdx.x; i < n4;
         i += gridDim.x * blockDim.x) {
      float4 v = s[i];
      u64 pk = (u64)pk2(v.x * sc, v.y * sc) |
               ((u64)pk2(v.z * sc, v.w * sc) << 32);
      *(u64*)&d[i * 4] = pk;
    }
  } else {
    __shared__ ushort_t T[64][72];
    const float* __restrict__ s = a.src[z];
    ushort_t* __restrict__ d = a.dst[z];
    const int bi = (blockIdx.x >> 4) * 64;   // source row block
    const int bj = (blockIdx.x & 15) * 64;   // source col block
    const int r = threadIdx.x >> 2;
    const int c = (threadIdx.x & 3) * 16;
    const float* sp = s + (size_t)(bi + r) * D_MODEL + bj + c;
    #pragma unroll
    for (int u = 0; u < 4; u++) {
      float4 v = *(const float4*)(sp + u * 4);
      T[c + u*4 + 0][r] = f2bf(v.x);
      T[c + u*4 + 1][r] = f2bf(v.y);
      T[c + u*4 + 2][r] = f2bf(v.z);
      T[c + u*4 + 3][r] = f2bf(v.w);
    }
    __syncthreads();
    ushort_t* dp = d + (size_t)(bj + r) * D_MODEL + bi + c;
    *(short8*)dp       = *(const short8*)&T[r][c];
    *(short8*)(dp + 8) = *(const short8*)&T[r][c + 8];
  }
}

struct MM3 {
  const ushort_t* a[3];
  const ushort_t* b[3];
  void*           c[3];
};

// ---------------------------------------------------------------------------
// 128x128 bf16 MFMA GEMM, BK=64 [validated R12-R15]. Used for qkv (768 blk,
// 3/CU: barrier drain hidden by inter-block overlap). z==2 computes
// vT = Weff_v . E^T directly (operand swap, R23). 2048 % 128 == 0 so
// blocks never straddle the batch boundary.
// ---------------------------------------------------------------------------
template<typename OutT>
__global__ __launch_bounds__(256)
void mm128_bt(MM3 pp, int lda, int ldb, int ldc, int K) {
  __shared__ ushort_t As[128 * 64];
  __shared__ ushort_t Bs[128 * 64];
  const int z = blockIdx.z;
  const ushort_t* __restrict__ A = pp.a[z];
  const ushort_t* __restrict__ B = pp.b[z];
  void* __restrict__ C = pp.c[z];

  const int tid  = threadIdx.x;
  const int lane = tid & 63;
  const int w    = tid >> 6;
  const int ww   = w >> 1, wc = w & 1;
  const int l15  = lane & 15, quad = lane >> 4;
  const bool swz2 = __is_same(OutT, ushort_t) && (z == 2);
  const int m0 = (swz2 ? blockIdx.y : blockIdx.x) * 128;
  const int n0 = (swz2 ? blockIdx.x : blockIdx.y) * 128;

  const ushort_t* gA[4];
  const ushort_t* gB[4];
  ushort_t* lA[4];
  ushort_t* lB[4];
  #pragma unroll
  for (int i = 0; i < 4; i++) {
    const int p  = w * 256 + i * 64 + lane;
    const int rw = p >> 3, cc = (p & 7) ^ (rw & 7);
    gA[i] = A + (size_t)(m0 + rw) * lda + cc * 8;
    gB[i] = B + (size_t)(n0 + rw) * ldb + cc * 8;
    lA[i] = &As[(w * 256 + i * 64) * 8];
    lB[i] = &Bs[(w * 256 + i * 64) * 8];
  }

  int iA[4][2], iB[4][2];
  #pragma unroll
  for (int mt = 0; mt < 4; mt++) {
    const int ra = ww * 64 + mt * 16 + l15;
    const int rb = wc * 64 + mt * 16 + l15;
    #pragma unroll
    for (int ks = 0; ks < 2; ks++) {
      iA[mt][ks] = (ra * 8 + ((ks * 4 + quad) ^ (ra & 7))) * 8;
      iB[mt][ks] = (rb * 8 + ((ks * 4 + quad) ^ (rb & 7))) * 8;
    }
  }

  f32x4 acc[4][4];
  #pragma unroll
  for (int i = 0; i < 4; i++)
    #pragma unroll
    for (int j = 0; j < 4; j++) acc[i][j] = (f32x4){0.f, 0.f, 0.f, 0.f};

  for (int k0 = 0; k0 < K; k0 += 64) {
    __syncthreads();
    #pragma unroll
    for (int i = 0; i < 4; i++) {
      gl16(gA[i] + k0, lA[i]);
      gl16(gB[i] + k0, lB[i]);
    }
    __syncthreads();

    #pragma unroll
    for (int ks = 0; ks < 2; ks++) {
      short8 af[4], bf[4];
      #pragma unroll
      for (int mt = 0; mt < 4; mt++) af[mt] = *(const short8*)&As[iA[mt][ks]];
      #pragma unroll
      for (int nt = 0; nt < 4; nt++) bf[nt] = *(const short8*)&Bs[iB[nt][ks]];
      #pragma unroll
      for (int mt = 0; mt < 4; mt++)
        #pragma unroll
        for (int nt = 0; nt < 4; nt++)
          acc[mt][nt] = __builtin_amdgcn_mfma_f32_16x16x32_bf16(
              af[mt], bf[nt], acc[mt][nt], 0, 0, 0);
    }
  }

  if constexpr (__is_same(OutT, ushort_t)) {
    if (z == 2) {
      // direct vT write: row=he, col=s (contiguous, coalesced)
      ushort_t* Cp = (ushort_t*)C + (size_t)(n0 >> 11) * D_MODEL * SEQ;
      const int c0 = (n0 & (SEQ - 1)) + wc * 64;
      #pragma unroll
      for (int mt = 0; mt < 4; mt++)
        #pragma unroll
        for (int nt = 0; nt < 4; nt++)
          #pragma unroll
          for (int r = 0; r < 4; r++) {
            const size_t row = (size_t)(m0 + ww * 64 + mt * 16 + quad * 4 + r);
            const int    col = c0 + nt * 16 + l15;
            Cp[row * SEQ + col] = f2bf(acc[mt][nt][r]);
          }
      return;
    }
  }

  #pragma unroll
  for (int mt = 0; mt < 4; mt++)
    #pragma unroll
    for (int nt = 0; nt < 4; nt++)
      #pragma unroll
      for (int r = 0; r < 4; r++) {
        const size_t row = (size_t)(m0 + ww * 64 + mt * 16 + quad * 4 + r);
        const int    col = n0 + wc * 64 + nt * 16 + l15;
        if constexpr (__is_same(OutT, float))
          ((float*)C)[row * ldc + col] = acc[mt][nt][r];
        else
          ((ushort_t*)C)[row * ldc + col] = f2bf(acc[mt][nt][r]);
      }
}

// ---------------------------------------------------------------------------
// R26: Weff GEMM with the E/WO fp32->bf16 conversions riding along as
// blockIdx.z==3 (mixed-body, same pattern as cvt_all). The cvt slice is
// pure-BW work (30MB) that previously serialized in cvt_all; here it
// overlaps Weff's compute-bound ~20µs. E-cvt completes within this
// dispatch -> safe for qkv; WO-cvt safe for out. z<3: mm64 body VERBATIM.
// ---------------------------------------------------------------------------
__global__ __launch_bounds__(256)
void weff_cvt(MM3 pp, const float4* __restrict__ Ef, ushort_t* __restrict__ Ebf,
              const float4* __restrict__ WOf, ushort_t* __restrict__ WOb) {
  const int z = blockIdx.z;
  if (z == 3) {
    // --- cvt slice: 256 blocks (x + 16y), grid-stride E (1M f4) + WO (256K)
    const int bid = blockIdx.x + (blockIdx.y << 4);
    const int n4E = (int)((size_t)BS_ROWS * D_MODEL >> 2);
    const int n4W = (D_MODEL * D_MODEL) >> 2;
    const int stride = 256 * 256;
    for (int i = bid * 256 + threadIdx.x; i < n4E; i += stride) {
      float4 v = Ef[i];
      u64 pk = (u64)pk2(v.x, v.y) | ((u64)pk2(v.z, v.w) << 32);
      *(u64*)&Ebf[i * 4] = pk;
    }
    for (int i = bid * 256 + threadIdx.x; i < n4W; i += stride) {
      float4 v = WOf[i];
      u64 pk = (u64)pk2(v.x, v.y) | ((u64)pk2(v.z, v.w) << 32);
      *(u64*)&WOb[i * 4] = pk;
    }
    return;
  }

  // --- mm64 body (R16, verbatim)
  __shared__ ushort_t As[64 * 64];
  __shared__ ushort_t Bs[64 * 64];
  const ushort_t* __restrict__ A = pp.a[z];
  const ushort_t* __restrict__ B = pp.b[z];
  void* __restrict__ C = pp.c[z];

  const int tid  = threadIdx.x;
  const int lane = tid & 63;
  const int w    = tid >> 6;
  const int wm   = w >> 1, wn = w & 1;
  const int l15  = lane & 15, quad = lane >> 4;
  const int m0 = blockIdx.x * 64;
  const int n0 = blockIdx.y * 64;

  const int p0 = tid, p1 = tid + 256;
  const int rw0 = p0 >> 3, cc0 = (p0 & 7) ^ (rw0 & 7);
  const int rw1 = p1 >> 3, cc1 = (p1 & 7) ^ (rw1 & 7);
  const ushort_t* gA0 = A + (size_t)(m0 + rw0) * D_MODEL + cc0 * 8;
  const ushort_t* gA1 = A + (size_t)(m0 + rw1) * D_MODEL + cc1 * 8;
  const ushort_t* gB0 = B + (size_t)(n0 + rw0) * D_MODEL + cc0 * 8;
  const ushort_t* gB1 = B + (size_t)(n0 + rw1) * D_MODEL + cc1 * 8;
  ushort_t* lA0 = &As[(w * 64) * 8];         // chunks w*64+lane
  ushort_t* lA1 = &As[(256 + w * 64) * 8];
  ushort_t* lB0 = &Bs[(w * 64) * 8];
  ushort_t* lB1 = &Bs[(256 + w * 64) * 8];

  int iA[2][2], iB[2][2];
  #pragma unroll
  for (int mt = 0; mt < 2; mt++) {
    const int ra = wm * 32 + mt * 16 + l15;
    const int rb = wn * 32 + mt * 16 + l15;
    #pragma unroll
    for (int ks = 0; ks < 2; ks++) {
      iA[mt][ks] = (ra * 8 + ((ks * 4 + quad) ^ (ra & 7))) * 8;
      iB[mt][ks] = (rb * 8 + ((ks * 4 + quad) ^ (rb & 7))) * 8;
    }
  }

  f32x4 acc[2][2];
  #pragma unroll
  for (int i = 0; i < 2; i++)
    #pragma unroll
    for (int j = 0; j < 2; j++) acc[i][j] = (f32x4){0.f, 0.f, 0.f, 0.f};

  for (int k0 = 0; k0 < D_MODEL; k0 += 64) {
    __syncthreads();
    gl16(gA0 + k0, lA0);
    gl16(gA1 + k0, lA1);
    gl16(gB0 + k0, lB0);
    gl16(gB1 + k0, lB1);
    __syncthreads();

    #pragma unroll
    for (int ks = 0; ks < 2; ks++) {
      short8 af[2], bf[2];
      #pragma unroll
      for (int mt = 0; mt < 2; mt++) af[mt] = *(const short8*)&As[iA[mt][ks]];
      #pragma unroll
      for (int nt = 0; nt < 2; nt++) bf[nt] = *(const short8*)&Bs[iB[nt][ks]];
      #pragma unroll
      for (int mt = 0; mt < 2; mt++)
        #pragma unroll
        for (int nt = 0; nt < 2; nt++)
          acc[mt][nt] = __builtin_amdgcn_mfma_f32_16x16x32_bf16(
              af[mt], bf[nt], acc[mt][nt], 0, 0, 0);
    }
  }

  #pragma unroll
  for (int mt = 0; mt < 2; mt++)
    #pragma unroll
    for (int nt = 0; nt < 2; nt++)
      #pragma unroll
      for (int r = 0; r < 4; r++) {
        const size_t row = (size_t)(m0 + wm * 32 + mt * 16 + quad * 4 + r);
        const int    col = n0 + wn * 32 + nt * 16 + l15;
        ((ushort_t*)C)[row * D_MODEL + col] = f2bf(acc[mt][nt][r]);
      }
}

// ---------------------------------------------------------------------------
// R16: 64x64-tile BK=64 GEMM. Kept for the out-projection (1024 blk, 4/CU —
// R22/R25: mm128@1/CU −10µs worse, mm12864@2/CU null; mm64 is measured
// best-or-equal).
// ---------------------------------------------------------------------------
template<typename OutT>
__global__ __launch_bounds__(256)
void mm64_bt(MM3 pp, int lda, int ldb, int ldc, int K) {
  __shared__ ushort_t As[64 * 64];
  __shared__ ushort_t Bs[64 * 64];
  const int z = blockIdx.z;
  const ushort_t* __restrict__ A = pp.a[z];
  const ushort_t* __restrict__ B = pp.b[z];
  void* __restrict__ C = pp.c[z];

  const int tid  = threadIdx.x;
  const int lane = tid & 63;
  const int w    = tid >> 6;
  const int wm   = w >> 1, wn = w & 1;
  const int l15  = lane & 15, quad = lane >> 4;
  const int m0 = blockIdx.x * 64;
  const int n0 = blockIdx.y * 64;

  const int p0 = tid, p1 = tid + 256;
  const int rw0 = p0 >> 3, cc0 = (p0 & 7) ^ (rw0 & 7);
  const int rw1 = p1 >> 3, cc1 = (p1 & 7) ^ (rw1 & 7);
  const ushort_t* gA0 = A + (size_t)(m0 + rw0) * lda + cc0 * 8;
  const ushort_t* gA1 = A + (size_t)(m0 + rw1) * lda + cc1 * 8;
  const ushort_t* gB0 = B + (size_t)(n0 + rw0) * ldb + cc0 * 8;
  const ushort_t* gB1 = B + (size_t)(n0 + rw1) * ldb + cc1 * 8;
  ushort_t* lA0 = &As[(w * 64) * 8];         // chunks w*64+lane
  ushort_t* lA1 = &As[(256 + w * 64) * 8];
  ushort_t* lB0 = &Bs[(w * 64) * 8];
  ushort_t* lB1 = &Bs[(256 + w * 64) * 8];

  int iA[2][2], iB[2][2];
  #pragma unroll
  for (int mt = 0; mt < 2; mt++) {
    const int ra = wm * 32 + mt * 16 + l15;
    const int rb = wn * 32 + mt * 16 + l15;
    #pragma unroll
    for (int ks = 0; ks < 2; ks++) {
      iA[mt][ks] = (ra * 8 + ((ks * 4 + quad) ^ (ra & 7))) * 8;
      iB[mt][ks] = (rb * 8 + ((ks * 4 + quad) ^ (rb & 7))) * 8;
    }
  }

  f32x4 acc[2][2];
  #pragma unroll
  for (int i = 0; i < 2; i++)
    #pragma unroll
    for (int j = 0; j < 2; j++) acc[i][j] = (f32x4){0.f, 0.f, 0.f, 0.f};

  for (int k0 = 0; k0 < K; k0 += 64) {
    __syncthreads();
    gl16(gA0 + k0, lA0);
    gl16(gA1 + k0, lA1);
    gl16(gB0 + k0, lB0);
    gl16(gB1 + k0, lB1);
    __syncthreads();

    #pragma unroll
    for (int ks = 0; ks < 2; ks++) {
      short8 af[2], bf[2];
      #pragma unroll
      for (int mt = 0; mt < 2; mt++) af[mt] = *(const short8*)&As[iA[mt][ks]];
      #pragma unroll
      for (int nt = 0; nt < 2; nt++) bf[nt] = *(const short8*)&Bs[iB[nt][ks]];
      #pragma unroll
      for (int mt = 0; mt < 2; mt++)
        #pragma unroll
        for (int nt = 0; nt < 2; nt++)
          acc[mt][nt] = __builtin_amdgcn_mfma_f32_16x16x32_bf16(
              af[mt], bf[nt], acc[mt][nt], 0, 0, 0);
    }
  }

  #pragma unroll
  for (int mt = 0; mt < 2; mt++)
    #pragma unroll
    for (int nt = 0; nt < 2; nt++)
      #pragma unroll
      for (int r = 0; r < 4; r++) {
        const size_t row = (size_t)(m0 + wm * 32 + mt * 16 + quad * 4 + r);
        const int    col = n0 + wn * 32 + nt * 16 + l15;
        if constexpr (__is_same(OutT, float))
          ((float*)C)[row * ldc + col] = acc[mt][nt][r];
        else
          ((ushort_t*)C)[row * ldc + col] = f2bf(acc[mt][nt][r]);
      }
}

// ---------------------------------------------------------------------------
// MFMA flash attention — R24 kernel VERBATIM (NSPLIT=1, writes ocat
// directly; combine deleted — 213.0 total, best). R17-R21: flash is bound
// by per-CU issue throughput of the QK->exp2->pack->PV stream.
// ---------------------------------------------------------------------------
#define QBLK 128
#define NIT (SEQ / 64)   // 32

__global__ __launch_bounds__(256)
void flash_attn(const ushort_t* __restrict__ q, const ushort_t* __restrict__ k,
                const ushort_t* __restrict__ vT, ushort_t* __restrict__ ocat) {
  const int q0    = blockIdx.x * QBLK;
  const int bh    = blockIdx.y;
  const int b = bh >> 4, h = bh & 15;
  const size_t row0 = (size_t)b * SEQ;
  const int hc    = h * EHEAD;

  __shared__ ushort_t Ks[64 * 64];   // swizzled chunks of [key][e]
  __shared__ ushort_t Vs[64 * 64];   // swizzled chunks of [e][key]

  const int tid  = threadIdx.x;
  const int lane = tid & 63;
  const int w    = tid >> 6;
  const int l31  = lane & 31;
  const int hi   = lane >> 5;
  const int q7v  = l31 & 7;
  const int qw   = w * 32;           // wave's 32 q-rows

  // Q B-fragments (B[e][q]: col=q=l31, k=e=es*16+hi*8+j), from global.
  short8 bq[4];
  {
    const ushort_t* src =
        q + (row0 + q0 + qw + l31) * D_MODEL + hc + hi * 8;
    #pragma unroll
    for (int es = 0; es < 4; es++)
      bq[es] = *(const short8*)(src + es * 16);
  }

  f32x16 ot[2];   // O^T[e=et*32+...][q=l31]
  #pragma unroll
  for (int r = 0; r < 16; r++) { ot[0][r] = 0.f; ot[1][r] = 0.f; }
  float lsum = 0.f;

  // staging: validated 512-chunk map (p -> row p>>3, slot (p&7)^(row&7))
  const int p0 = tid, p1 = tid + 256;
  const int rw0 = p0 >> 3, cc0 = (p0 & 7) ^ (rw0 & 7);
  const int rw1 = p1 >> 3, cc1 = (p1 & 7) ^ (rw1 & 7);
  const ushort_t* kg0 = k + (row0 + rw0) * D_MODEL + hc + cc0 * 8;   // +kt*D
  const ushort_t* kg1 = k + (row0 + rw1) * D_MODEL + hc + cc1 * 8;
  const ushort_t* vg0 = vT + ((size_t)(b * D_MODEL + hc + rw0)) * SEQ + cc0 * 8;
  const ushort_t* vg1 = vT + ((size_t)(b * D_MODEL + hc + rw1)) * SEQ + cc1 * 8;

  // precomputed swizzled read slots
  int slotK[4];          // QK^T A-frag: e-chunk (es*2+hi) ^ q7v
  #pragma unroll
  for (int es = 0; es < 4; es++) slotK[es] = (((es * 2 + hi) ^ q7v)) * 8;
  int slotV[2][2];       // PV A-frag: key-chunk (mt*4+ks2*2+hi) ^ q7v
  #pragma unroll
  for (int mt = 0; mt < 2; mt++)
    #pragma unroll
    for (int ks2 = 0; ks2 < 2; ks2++)
      slotV[mt][ks2] = (((mt * 4 + ks2 * 2 + hi) ^ q7v)) * 8;

  short8 kr0, kr1, vr0, vr1;
  {
    kr0 = *(const short8*)(kg0);
    kr1 = *(const short8*)(kg1);
    vr0 = *(const short8*)(vg0);
    vr1 = *(const short8*)(vg1);
  }
  *(short8*)&Ks[p0 * 8] = kr0;
  *(short8*)&Ks[p1 * 8] = kr1;
  *(short8*)&Vs[p0 * 8] = vr0;
  *(short8*)&Vs[p1 * 8] = vr1;

  for (int it = 0; it < NIT; it++) {
    __syncthreads();   // staged LDS visible to all waves

    if (it + 1 < NIT) {
      const int kn = (it + 1) * 64;
      const size_t ko = (size_t)kn * D_MODEL;
      kr0 = *(const short8*)(kg0 + ko);
      kr1 = *(const short8*)(kg1 + ko);
      vr0 = *(const short8*)(vg0 + kn);
      vr1 = *(const short8*)(vg1 + kn);
    }

    #pragma unroll
    for (int mt = 0; mt < 2; mt++) {       // two 32-key chunks
      // --- S^T chunk = K . Q^T  (A: row=key=mt*32+l31, k=e slice)
      f32x16 st;
      #pragma unroll
      for (int r = 0; r < 16; r++) st[r] = 0.f;
      short8 af[4];
      #pragma unroll
      for (int es = 0; es < 4; es++)
        af[es] = *(const short8*)&Ks[(mt * 32 + l31) * 64 + slotK[es]];
      __builtin_amdgcn_s_setprio(1);
      #pragma unroll
      for (int es = 0; es < 4; es++)
        st = __builtin_amdgcn_mfma_f32_32x32x16_bf16(af[es], bq[es], st,
                                                     0, 0, 0);
      __builtin_amdgcn_s_setprio(0);

      // --- in-register softmax: exp2 (log2e pre-folded) + tree sums
      #pragma unroll
      for (int r = 0; r < 16; r++) st[r] = __builtin_amdgcn_exp2f(st[r]);
      lsum += (((st[0] + st[1]) + (st[2] + st[3])) +
               ((st[4] + st[5]) + (st[6] + st[7]))) +
              (((st[8] + st[9]) + (st[10] + st[11])) +
               ((st[12] + st[13]) + (st[14] + st[15])));

      // --- P^T B-frags: pk2 pairs + permlane32_swap (lane needs keys
      // hi*8..+7 of each 16-key slice; swap exchanges vdst.hi <-> vsrc.lo)
      unsigned a0 = pk2(st[0],  st[1]),  b0 = pk2(st[2],  st[3]);
      unsigned c0 = pk2(st[4],  st[5]),  d0 = pk2(st[6],  st[7]);
      unsigned a1 = pk2(st[8],  st[9]),  b1 = pk2(st[10], st[11]);
      unsigned c1 = pk2(st[12], st[13]), d1 = pk2(st[14], st[15]);
      asm volatile("v_permlane32_swap_b32 %0, %1" : "+v"(a0), "+v"(c0));
      asm volatile("v_permlane32_swap_b32 %0, %1" : "+v"(b0), "+v"(d0));
      asm volatile("v_permlane32_swap_b32 %0, %1" : "+v"(a1), "+v"(c1));
      asm volatile("v_permlane32_swap_b32 %0, %1" : "+v"(b1), "+v"(d1));
      short8 pb[2];
      { U4S8 u; u.u[0] = a0; u.u[1] = b0; u.u[2] = c0; u.u[3] = d0; pb[0] = u.s; }
      { U4S8 u; u.u[0] = a1; u.u[1] = b1; u.u[2] = c1; u.u[3] = d1; pb[1] = u.s; }

      // --- O^T += V^T . P^T  (A: row=e=et*32+l31, k=key slice)
      short8 av[2][2];
      #pragma unroll
      for (int et = 0; et < 2; et++)
        #pragma unroll
        for (int ks2 = 0; ks2 < 2; ks2++)
          av[et][ks2] =
              *(const short8*)&Vs[(et * 32 + l31) * 64 + slotV[mt][ks2]];
      __builtin_amdgcn_s_setprio(1);
      #pragma unroll
      for (int et = 0; et < 2; et++)
        #pragma unroll
        for (int ks2 = 0; ks2 < 2; ks2++)
          ot[et] = __builtin_amdgcn_mfma_f32_32x32x16_bf16(
              av[et][ks2], pb[ks2], ot[et], 0, 0, 0);
      __builtin_amdgcn_s_setprio(0);
    }

    __syncthreads();   // all waves done reading Ks/Vs
    if (it + 1 < NIT) {
      *(short8*)&Ks[p0 * 8] = kr0;
      *(short8*)&Ks[p1 * 8] = kr1;
      *(short8*)&Vs[p0 * 8] = vr0;
      *(short8*)&Vs[p1 * 8] = vr1;
    }
  }

  // --- epilogue: normalize and write FINAL output directly to ocat
  // (layout [b][s][h*EHEAD+e]; reg r=rq*4+j -> e = et*32 + 8*rq + 4*hi + j)
  {
    const float s = lsum + __shfl_xor(lsum, 32);
    const float inv = 1.f / s;
    const int qL = q0 + qw + l31;
    ushort_t* orow = ocat + ((size_t)(b * SEQ + qL)) * D_MODEL + hc;
    #pragma unroll
    for (int et = 0; et < 2; et++)
      #pragma unroll
      for (int rq = 0; rq < 4; rq++) {
        const int e0 = et * 32 + rq * 8 + hi * 4;
        u64 pk = (u64)pk2(ot[et][rq * 4 + 0] * inv, ot[et][rq * 4 + 1] * inv) |
                 ((u64)pk2(ot[et][rq * 4 + 2] * inv, ot[et][rq * 4 + 3] * inv)
                  << 32);
        *(u64*)&orow[e0] = pk;
      }
  }
}

// ---------------------------------------------------------------------------
// 5 dispatches (R26: cvt_all split; E/WO cvt overlapped under Weff):
//  0. cvt_pre  (H scaled + W^T transposed — only what Weff needs; ~18MB)
//  1. weff_cvt (mm64 Weff z<3, 768 blk) + z=3 cvt of E+WO (256 blk, ~30MB
//     pure-BW hidden under the GEMM)
//  2. qkv_z  = E @ Weff_z^T       (mm128, 768 blk; z=2 operand-swapped)
//  3. flash NSPLIT=1              (R24: 512 blk, writes ocat directly)
//  4. out = ocat @ WO^T (fp32)    (mm64: 1024 blk, 4/CU)
// ws: 76.5 MB (R14 layout; Opart/lpart unused).
// ---------------------------------------------------------------------------
extern "C" void kernel_launch(void* const* d_in, const int* in_sizes, int n_in,
                              void* d_out, int out_size, void* d_ws, size_t ws_size,
                              hipStream_t stream) {
  const float* E  = (const float*)d_in[0];
  const float* WQ = (const float*)d_in[1];
  const float* WK = (const float*)d_in[2];
  const float* WV = (const float*)d_in[3];
  const float* WO = (const float*)d_in[4];
  const float* HQ = (const float*)d_in[5];
  const float* HK = (const float*)d_in[6];
  const float* HV = (const float*)d_in[7];
  float* out = (float*)d_out;

  const size_t NE = (size_t)BS_ROWS * D_MODEL;  // 4M
  const size_t NW = (size_t)D_MODEL * D_MODEL;  // 1M

  ushort_t* Ebf   = (ushort_t*)d_ws;            // 4M
  ushort_t* WOb   = Ebf + NE;                   // 1M
  ushort_t* Hb    = WOb + NW;                   // 3 x 1M
  ushort_t* Wt    = Hb + 3 * NW;                // 3 x 1M (W^T)
  ushort_t* Weff  = Wt + 3 * NW;                // 3 x 1M
  ushort_t* qb    = Weff + 3 * NW;              // 4M
  ushort_t* kb    = qb + NE;                    // 4M
  ushort_t* vTb   = kb + NE;                    // 4M ([b][he][s])
  ushort_t* ocat  = vTb + NE;                   // 4M

  // 0. cvt_pre: H (HQ scaled by 0.125*log2e) + W^T transposes
  {
    CvtPre a;
    const float* s2[6] = {HQ, HK, HV, WQ, WK, WV};
    ushort_t* dsts[6] = {Hb, Hb + NW, Hb + 2 * NW, Wt, Wt + NW, Wt + 2 * NW};
    for (int i = 0; i < 6; i++) {
      a.src[i] = s2[i]; a.dst[i] = dsts[i];
      a.scale[i] = (i == 0) ? (0.125f * 1.44269504088896f) : 1.0f;
    }
    cvt_pre<<<dim3(256, 6), 256, 0, stream>>>(a);
  }
  // 1. Weff_z = H_z @ W_z (z<3, mm64 body) + E/WO cvt (z=3, overlapped)
  {
    MM3 p;
    p.a[0] = Hb; p.a[1] = Hb + NW; p.a[2] = Hb + 2 * NW;
    p.b[0] = Wt; p.b[1] = Wt + NW; p.b[2] = Wt + 2 * NW;
    p.c[0] = Weff; p.c[1] = Weff + NW; p.c[2] = Weff + 2 * NW;
    weff_cvt<<<dim3(16, 16, 4), 256, 0, stream>>>(
        p, (const float4*)E, Ebf, (const float4*)WO, WOb);
  }
  // 2. qkv_z = E @ Weff_z^T  (z=2: A=Weff_v, B=Ebf -> vT direct)
  {
    MM3 p;
    p.a[0] = Ebf; p.a[1] = Ebf; p.a[2] = Weff + 2 * NW;
    p.b[0] = Weff; p.b[1] = Weff + NW; p.b[2] = Ebf;
    p.c[0] = qb; p.c[1] = kb; p.c[2] = vTb;
    mm128_bt<ushort_t><<<dim3(32, 8, 3), 256, 0, stream>>>(
        p, D_MODEL, D_MODEL, D_MODEL, D_MODEL);
  }
  // 3. flash NSPLIT=1 (16 x 32 = 512 blocks) -> ocat directly
  flash_attn<<<dim3(SEQ / QBLK, 32), 256, 0, stream>>>(qb, kb, vTb, ocat);
  // 4. out = ocat @ WO^T  (64-tile; 1024 blocks, 4/CU)
  {
    MM3 p;
    p.a[0] = ocat; p.b[0] = WOb; p.c[0] = out;
    p.a[1] = ocat; p.b[1] = WOb; p.c[1] = out;
    p.a[2] = ocat; p.b[2] = WOb; p.c[2] = out;
    mm64_bt<float><<<dim3(64, 16, 1), 256, 0, stream>>>(
        p, D_MODEL, D_MODEL, D_MODEL, D_MODEL);
  }
}

// Round 12
// 205.706 us; speedup vs baseline: 1.0375x; 1.0091x over previous
//
#include <hip/hip_runtime.h>
#include <hip/hip_bf16.h>
#include <math.h>

#define D_MODEL 1024
#define BATCH   2
#define SEQ     2048
#define NHEAD   16
#define EHEAD   64
#define BS_ROWS (BATCH*SEQ)   // 4096

typedef unsigned short ushort_t;
typedef unsigned long long u64;
typedef __attribute__((ext_vector_type(8))) short short8;   // 8 bf16 = 4 VGPRs
typedef __attribute__((ext_vector_type(4))) float f32x4;    // MFMA C/D 16x16
typedef __attribute__((ext_vector_type(16))) float f32x16;  // MFMA C/D 32x32

union U4S8 { unsigned u[4]; short8 s; };

static __device__ __forceinline__ ushort_t f2bf(float x) {
  __hip_bfloat16 h = __float2bfloat16(x);
  return *reinterpret_cast<ushort_t*>(&h);
}
static __device__ __forceinline__ unsigned pk2(float a, float b) {
  __hip_bfloat162 t = __float22bfloat162_rn(make_float2(a, b));
  return *reinterpret_cast<unsigned*>(&t);
}
static __device__ __forceinline__ float bf2f(ushort_t u) {
  unsigned x = (unsigned)u << 16;
  return *reinterpret_cast<float*>(&x);
}

// async global->LDS, 16B/lane; LDS dest = wave-uniform base + lane*16
static __device__ __forceinline__ void gl16(const void* g, void* l) {
  __builtin_amdgcn_global_load_lds(
      (const __attribute__((address_space(1))) void*)g,
      (__attribute__((address_space(3))) void*)l, 16, 0, 0);
}

// ---------------------------------------------------------------------------
// R26 cvt_pre: ONLY what Weff needs — z<3 plain fp32->bf16 of H
// (HQ*0.125*log2e, HK, HV); z 3..5 transposing cvt (WQ^T/WK^T/WV^T).
// E and WO conversion moved into the Weff dispatch (overlap, R26).
// ---------------------------------------------------------------------------
struct CvtPre {
  const float* src[6];
  ushort_t*    dst[6];
  float        scale[6];
};

__global__ __launch_bounds__(256) void cvt_pre(CvtPre a) {
  const int z = blockIdx.y;
  if (z < 3) {
    const float4* __restrict__ s = (const float4*)a.src[z];
    ushort_t* __restrict__ d = a.dst[z];
    const float sc = a.scale[z];
    const int n4 = (D_MODEL * D_MODEL) >> 2;
    for (int i = blockIdx.x * blockDim.x + threadIdx.x; i < n4;
         i += gridDim.x * blockDim.x) {
      float4 v = s[i];
      u64 pk = (u64)pk2(v.x * sc, v.y * sc) |
               ((u64)pk2(v.z * sc, v.w * sc) << 32);
      *(u64*)&d[i * 4] = pk;
    }
  } else {
    __shared__ ushort_t T[64][72];
    const float* __restrict__ s = a.src[z];
    ushort_t* __restrict__ d = a.dst[z];
    const int bi = (blockIdx.x >> 4) * 64;   // source row block
    const int bj = (blockIdx.x & 15) * 64;   // source col block
    const int r = threadIdx.x >> 2;
    const int c = (threadIdx.x & 3) * 16;
    const float* sp = s + (size_t)(bi + r) * D_MODEL + bj + c;
    #pragma unroll
    for (int u = 0; u < 4; u++) {
      float4 v = *(const float4*)(sp + u * 4);
      T[c + u*4 + 0][r] = f2bf(v.x);
      T[c + u*4 + 1][r] = f2bf(v.y);
      T[c + u*4 + 2][r] = f2bf(v.z);
      T[c + u*4 + 3][r] = f2bf(v.w);
    }
    __syncthreads();
    ushort_t* dp = d + (size_t)(bj + r) * D_MODEL + bi + c;
    *(short8*)dp       = *(const short8*)&T[r][c];
    *(short8*)(dp + 8) = *(const short8*)&T[r][c + 8];
  }
}

struct MM3 {
  const ushort_t* a[3];
  const ushort_t* b[3];
  void*           c[3];
};

// ---------------------------------------------------------------------------
// 128x128 bf16 MFMA GEMM, BK=64 [validated R12-R15]. Used for qkv (768 blk,
// 3/CU: barrier drain hidden by inter-block overlap). z==2 computes
// vT = Weff_v . E^T directly (operand swap, R23). 2048 % 128 == 0 so
// blocks never straddle the batch boundary.
// ---------------------------------------------------------------------------
template<typename OutT>
__global__ __launch_bounds__(256)
void mm128_bt(MM3 pp, int lda, int ldb, int ldc, int K) {
  __shared__ ushort_t As[128 * 64];
  __shared__ ushort_t Bs[128 * 64];
  const int z = blockIdx.z;
  const ushort_t* __restrict__ A = pp.a[z];
  const ushort_t* __restrict__ B = pp.b[z];
  void* __restrict__ C = pp.c[z];

  const int tid  = threadIdx.x;
  const int lane = tid & 63;
  const int w    = tid >> 6;
  const int ww   = w >> 1, wc = w & 1;
  const int l15  = lane & 15, quad = lane >> 4;
  const bool swz2 = __is_same(OutT, ushort_t) && (z == 2);
  const int m0 = (swz2 ? blockIdx.y : blockIdx.x) * 128;
  const int n0 = (swz2 ? blockIdx.x : blockIdx.y) * 128;

  const ushort_t* gA[4];
  const ushort_t* gB[4];
  ushort_t* lA[4];
  ushort_t* lB[4];
  #pragma unroll
  for (int i = 0; i < 4; i++) {
    const int p  = w * 256 + i * 64 + lane;
    const int rw = p >> 3, cc = (p & 7) ^ (rw & 7);
    gA[i] = A + (size_t)(m0 + rw) * lda + cc * 8;
    gB[i] = B + (size_t)(n0 + rw) * ldb + cc * 8;
    lA[i] = &As[(w * 256 + i * 64) * 8];
    lB[i] = &Bs[(w * 256 + i * 64) * 8];
  }

  int iA[4][2], iB[4][2];
  #pragma unroll
  for (int mt = 0; mt < 4; mt++) {
    const int ra = ww * 64 + mt * 16 + l15;
    const int rb = wc * 64 + mt * 16 + l15;
    #pragma unroll
    for (int ks = 0; ks < 2; ks++) {
      iA[mt][ks] = (ra * 8 + ((ks * 4 + quad) ^ (ra & 7))) * 8;
      iB[mt][ks] = (rb * 8 + ((ks * 4 + quad) ^ (rb & 7))) * 8;
    }
  }

  f32x4 acc[4][4];
  #pragma unroll
  for (int i = 0; i < 4; i++)
    #pragma unroll
    for (int j = 0; j < 4; j++) acc[i][j] = (f32x4){0.f, 0.f, 0.f, 0.f};

  for (int k0 = 0; k0 < K; k0 += 64) {
    __syncthreads();
    #pragma unroll
    for (int i = 0; i < 4; i++) {
      gl16(gA[i] + k0, lA[i]);
      gl16(gB[i] + k0, lB[i]);
    }
    __syncthreads();

    #pragma unroll
    for (int ks = 0; ks < 2; ks++) {
      short8 af[4], bf[4];
      #pragma unroll
      for (int mt = 0; mt < 4; mt++) af[mt] = *(const short8*)&As[iA[mt][ks]];
      #pragma unroll
      for (int nt = 0; nt < 4; nt++) bf[nt] = *(const short8*)&Bs[iB[nt][ks]];
      #pragma unroll
      for (int mt = 0; mt < 4; mt++)
        #pragma unroll
        for (int nt = 0; nt < 4; nt++)
          acc[mt][nt] = __builtin_amdgcn_mfma_f32_16x16x32_bf16(
              af[mt], bf[nt], acc[mt][nt], 0, 0, 0);
    }
  }

  if constexpr (__is_same(OutT, ushort_t)) {
    if (z == 2) {
      // direct vT write: row=he, col=s (contiguous, coalesced)
      ushort_t* Cp = (ushort_t*)C + (size_t)(n0 >> 11) * D_MODEL * SEQ;
      const int c0 = (n0 & (SEQ - 1)) + wc * 64;
      #pragma unroll
      for (int mt = 0; mt < 4; mt++)
        #pragma unroll
        for (int nt = 0; nt < 4; nt++)
          #pragma unroll
          for (int r = 0; r < 4; r++) {
            const size_t row = (size_t)(m0 + ww * 64 + mt * 16 + quad * 4 + r);
            const int    col = c0 + nt * 16 + l15;
            Cp[row * SEQ + col] = f2bf(acc[mt][nt][r]);
          }
      return;
    }
  }

  #pragma unroll
  for (int mt = 0; mt < 4; mt++)
    #pragma unroll
    for (int nt = 0; nt < 4; nt++)
      #pragma unroll
      for (int r = 0; r < 4; r++) {
        const size_t row = (size_t)(m0 + ww * 64 + mt * 16 + quad * 4 + r);
        const int    col = n0 + wc * 64 + nt * 16 + l15;
        if constexpr (__is_same(OutT, float))
          ((float*)C)[row * ldc + col] = acc[mt][nt][r];
        else
          ((ushort_t*)C)[row * ldc + col] = f2bf(acc[mt][nt][r]);
      }
}

// ---------------------------------------------------------------------------
// R26: Weff GEMM with the E/WO fp32->bf16 conversions riding along as
// blockIdx.z==3 (mixed-body). The cvt slice is pure-BW work (30MB) hidden
// under Weff's compute. z<3: mm64 body VERBATIM.
// ---------------------------------------------------------------------------
__global__ __launch_bounds__(256)
void weff_cvt(MM3 pp, const float4* __restrict__ Ef, ushort_t* __restrict__ Ebf,
              const float4* __restrict__ WOf, ushort_t* __restrict__ WOb) {
  const int z = blockIdx.z;
  if (z == 3) {
    // --- cvt slice: 256 blocks (x + 16y), grid-stride E (1M f4) + WO (256K)
    const int bid = blockIdx.x + (blockIdx.y << 4);
    const int n4E = (int)((size_t)BS_ROWS * D_MODEL >> 2);
    const int n4W = (D_MODEL * D_MODEL) >> 2;
    const int stride = 256 * 256;
    for (int i = bid * 256 + threadIdx.x; i < n4E; i += stride) {
      float4 v = Ef[i];
      u64 pk = (u64)pk2(v.x, v.y) | ((u64)pk2(v.z, v.w) << 32);
      *(u64*)&Ebf[i * 4] = pk;
    }
    for (int i = bid * 256 + threadIdx.x; i < n4W; i += stride) {
      float4 v = WOf[i];
      u64 pk = (u64)pk2(v.x, v.y) | ((u64)pk2(v.z, v.w) << 32);
      *(u64*)&WOb[i * 4] = pk;
    }
    return;
  }

  // --- mm64 body (R16, verbatim)
  __shared__ ushort_t As[64 * 64];
  __shared__ ushort_t Bs[64 * 64];
  const ushort_t* __restrict__ A = pp.a[z];
  const ushort_t* __restrict__ B = pp.b[z];
  void* __restrict__ C = pp.c[z];

  const int tid  = threadIdx.x;
  const int lane = tid & 63;
  const int w    = tid >> 6;
  const int wm   = w >> 1, wn = w & 1;
  const int l15  = lane & 15, quad = lane >> 4;
  const int m0 = blockIdx.x * 64;
  const int n0 = blockIdx.y * 64;

  const int p0 = tid, p1 = tid + 256;
  const int rw0 = p0 >> 3, cc0 = (p0 & 7) ^ (rw0 & 7);
  const int rw1 = p1 >> 3, cc1 = (p1 & 7) ^ (rw1 & 7);
  const ushort_t* gA0 = A + (size_t)(m0 + rw0) * D_MODEL + cc0 * 8;
  const ushort_t* gA1 = A + (size_t)(m0 + rw1) * D_MODEL + cc1 * 8;
  const ushort_t* gB0 = B + (size_t)(n0 + rw0) * D_MODEL + cc0 * 8;
  const ushort_t* gB1 = B + (size_t)(n0 + rw1) * D_MODEL + cc1 * 8;
  ushort_t* lA0 = &As[(w * 64) * 8];         // chunks w*64+lane
  ushort_t* lA1 = &As[(256 + w * 64) * 8];
  ushort_t* lB0 = &Bs[(w * 64) * 8];
  ushort_t* lB1 = &Bs[(256 + w * 64) * 8];

  int iA[2][2], iB[2][2];
  #pragma unroll
  for (int mt = 0; mt < 2; mt++) {
    const int ra = wm * 32 + mt * 16 + l15;
    const int rb = wn * 32 + mt * 16 + l15;
    #pragma unroll
    for (int ks = 0; ks < 2; ks++) {
      iA[mt][ks] = (ra * 8 + ((ks * 4 + quad) ^ (ra & 7))) * 8;
      iB[mt][ks] = (rb * 8 + ((ks * 4 + quad) ^ (rb & 7))) * 8;
    }
  }

  f32x4 acc[2][2];
  #pragma unroll
  for (int i = 0; i < 2; i++)
    #pragma unroll
    for (int j = 0; j < 2; j++) acc[i][j] = (f32x4){0.f, 0.f, 0.f, 0.f};

  for (int k0 = 0; k0 < D_MODEL; k0 += 64) {
    __syncthreads();
    gl16(gA0 + k0, lA0);
    gl16(gA1 + k0, lA1);
    gl16(gB0 + k0, lB0);
    gl16(gB1 + k0, lB1);
    __syncthreads();

    #pragma unroll
    for (int ks = 0; ks < 2; ks++) {
      short8 af[2], bf[2];
      #pragma unroll
      for (int mt = 0; mt < 2; mt++) af[mt] = *(const short8*)&As[iA[mt][ks]];
      #pragma unroll
      for (int nt = 0; nt < 2; nt++) bf[nt] = *(const short8*)&Bs[iB[nt][ks]];
      #pragma unroll
      for (int mt = 0; mt < 2; mt++)
        #pragma unroll
        for (int nt = 0; nt < 2; nt++)
          acc[mt][nt] = __builtin_amdgcn_mfma_f32_16x16x32_bf16(
              af[mt], bf[nt], acc[mt][nt], 0, 0, 0);
    }
  }

  #pragma unroll
  for (int mt = 0; mt < 2; mt++)
    #pragma unroll
    for (int nt = 0; nt < 2; nt++)
      #pragma unroll
      for (int r = 0; r < 4; r++) {
        const size_t row = (size_t)(m0 + wm * 32 + mt * 16 + quad * 4 + r);
        const int    col = n0 + wn * 32 + nt * 16 + l15;
        ((ushort_t*)C)[row * D_MODEL + col] = f2bf(acc[mt][nt][r]);
      }
}

// ---------------------------------------------------------------------------
// R16: 64x64-tile BK=64 GEMM. Kept for the out-projection (1024 blk, 4/CU —
// R22/R25: mm128@1/CU −10µs worse, mm12864@2/CU null; mm64 measured best).
// ---------------------------------------------------------------------------
template<typename OutT>
__global__ __launch_bounds__(256)
void mm64_bt(MM3 pp, int lda, int ldb, int ldc, int K) {
  __shared__ ushort_t As[64 * 64];
  __shared__ ushort_t Bs[64 * 64];
  const int z = blockIdx.z;
  const ushort_t* __restrict__ A = pp.a[z];
  const ushort_t* __restrict__ B = pp.b[z];
  void* __restrict__ C = pp.c[z];

  const int tid  = threadIdx.x;
  const int lane = tid & 63;
  const int w    = tid >> 6;
  const int wm   = w >> 1, wn = w & 1;
  const int l15  = lane & 15, quad = lane >> 4;
  const int m0 = blockIdx.x * 64;
  const int n0 = blockIdx.y * 64;

  const int p0 = tid, p1 = tid + 256;
  const int rw0 = p0 >> 3, cc0 = (p0 & 7) ^ (rw0 & 7);
  const int rw1 = p1 >> 3, cc1 = (p1 & 7) ^ (rw1 & 7);
  const ushort_t* gA0 = A + (size_t)(m0 + rw0) * lda + cc0 * 8;
  const ushort_t* gA1 = A + (size_t)(m0 + rw1) * lda + cc1 * 8;
  const ushort_t* gB0 = B + (size_t)(n0 + rw0) * ldb + cc0 * 8;
  const ushort_t* gB1 = B + (size_t)(n0 + rw1) * ldb + cc1 * 8;
  ushort_t* lA0 = &As[(w * 64) * 8];         // chunks w*64+lane
  ushort_t* lA1 = &As[(256 + w * 64) * 8];
  ushort_t* lB0 = &Bs[(w * 64) * 8];
  ushort_t* lB1 = &Bs[(256 + w * 64) * 8];

  int iA[2][2], iB[2][2];
  #pragma unroll
  for (int mt = 0; mt < 2; mt++) {
    const int ra = wm * 32 + mt * 16 + l15;
    const int rb = wn * 32 + mt * 16 + l15;
    #pragma unroll
    for (int ks = 0; ks < 2; ks++) {
      iA[mt][ks] = (ra * 8 + ((ks * 4 + quad) ^ (ra & 7))) * 8;
      iB[mt][ks] = (rb * 8 + ((ks * 4 + quad) ^ (rb & 7))) * 8;
    }
  }

  f32x4 acc[2][2];
  #pragma unroll
  for (int i = 0; i < 2; i++)
    #pragma unroll
    for (int j = 0; j < 2; j++) acc[i][j] = (f32x4){0.f, 0.f, 0.f, 0.f};

  for (int k0 = 0; k0 < K; k0 += 64) {
    __syncthreads();
    gl16(gA0 + k0, lA0);
    gl16(gA1 + k0, lA1);
    gl16(gB0 + k0, lB0);
    gl16(gB1 + k0, lB1);
    __syncthreads();

    #pragma unroll
    for (int ks = 0; ks < 2; ks++) {
      short8 af[2], bf[2];
      #pragma unroll
      for (int mt = 0; mt < 2; mt++) af[mt] = *(const short8*)&As[iA[mt][ks]];
      #pragma unroll
      for (int nt = 0; nt < 2; nt++) bf[nt] = *(const short8*)&Bs[iB[nt][ks]];
      #pragma unroll
      for (int mt = 0; mt < 2; mt++)
        #pragma unroll
        for (int nt = 0; nt < 2; nt++)
          acc[mt][nt] = __builtin_amdgcn_mfma_f32_16x16x32_bf16(
              af[mt], bf[nt], acc[mt][nt], 0, 0, 0);
    }
  }

  #pragma unroll
  for (int mt = 0; mt < 2; mt++)
    #pragma unroll
    for (int nt = 0; nt < 2; nt++)
      #pragma unroll
      for (int r = 0; r < 4; r++) {
        const size_t row = (size_t)(m0 + wm * 32 + mt * 16 + quad * 4 + r);
        const int    col = n0 + wn * 32 + nt * 16 + l15;
        if constexpr (__is_same(OutT, float))
          ((float*)C)[row * ldc + col] = acc[mt][nt][r];
        else
          ((ushort_t*)C)[row * ldc + col] = f2bf(acc[mt][nt][r]);
      }
}

// ---------------------------------------------------------------------------
// MFMA flash attention — R27: R24 structure with the two 32-key chunks'
// pipelines INTERLEAVED for per-wave ILP. The serial chain per chunk
// (QK MFMA -> exp2 TRANS -> pack VALU -> PV MFMA) left each pipe idle
// while the other ran; with only 2 waves/SIMD (grid-fixed 2048 waves)
// TLP can't fill the gaps. Now: af reads (both chunks) -> QK0+QK1 MFMAs
// issued back-to-back -> softmax0 (exp2/pack overlaps QK1's MFMA
// execution) -> softmax1 -> av reads -> PV0+PV1. Same math, same LDS,
// register lifetimes staged so peak ~150 VGPR (2 waves/SIMD kept).
// ---------------------------------------------------------------------------
#define QBLK 128
#define NIT (SEQ / 64)   // 32

__global__ __launch_bounds__(256)
void flash_attn(const ushort_t* __restrict__ q, const ushort_t* __restrict__ k,
                const ushort_t* __restrict__ vT, ushort_t* __restrict__ ocat) {
  const int q0    = blockIdx.x * QBLK;
  const int bh    = blockIdx.y;
  const int b = bh >> 4, h = bh & 15;
  const size_t row0 = (size_t)b * SEQ;
  const int hc    = h * EHEAD;

  __shared__ ushort_t Ks[64 * 64];   // swizzled chunks of [key][e]
  __shared__ ushort_t Vs[64 * 64];   // swizzled chunks of [e][key]

  const int tid  = threadIdx.x;
  const int lane = tid & 63;
  const int w    = tid >> 6;
  const int l31  = lane & 31;
  const int hi   = lane >> 5;
  const int q7v  = l31 & 7;
  const int qw   = w * 32;           // wave's 32 q-rows

  // Q B-fragments (B[e][q]: col=q=l31, k=e=es*16+hi*8+j), from global.
  short8 bq[4];
  {
    const ushort_t* src =
        q + (row0 + q0 + qw + l31) * D_MODEL + hc + hi * 8;
    #pragma unroll
    for (int es = 0; es < 4; es++)
      bq[es] = *(const short8*)(src + es * 16);
  }

  f32x16 ot[2];   // O^T[e=et*32+...][q=l31]
  #pragma unroll
  for (int r = 0; r < 16; r++) { ot[0][r] = 0.f; ot[1][r] = 0.f; }
  float lsum = 0.f;

  // staging: validated 512-chunk map (p -> row p>>3, slot (p&7)^(row&7))
  const int p0 = tid, p1 = tid + 256;
  const int rw0 = p0 >> 3, cc0 = (p0 & 7) ^ (rw0 & 7);
  const int rw1 = p1 >> 3, cc1 = (p1 & 7) ^ (rw1 & 7);
  const ushort_t* kg0 = k + (row0 + rw0) * D_MODEL + hc + cc0 * 8;   // +kt*D
  const ushort_t* kg1 = k + (row0 + rw1) * D_MODEL + hc + cc1 * 8;
  const ushort_t* vg0 = vT + ((size_t)(b * D_MODEL + hc + rw0)) * SEQ + cc0 * 8;
  const ushort_t* vg1 = vT + ((size_t)(b * D_MODEL + hc + rw1)) * SEQ + cc1 * 8;

  // precomputed swizzled read slots
  int slotK[4];          // QK^T A-frag: e-chunk (es*2+hi) ^ q7v
  #pragma unroll
  for (int es = 0; es < 4; es++) slotK[es] = (((es * 2 + hi) ^ q7v)) * 8;
  int slotV[2][2];       // PV A-frag: key-chunk (mt*4+ks2*2+hi) ^ q7v
  #pragma unroll
  for (int mt = 0; mt < 2; mt++)
    #pragma unroll
    for (int ks2 = 0; ks2 < 2; ks2++)
      slotV[mt][ks2] = (((mt * 4 + ks2 * 2 + hi) ^ q7v)) * 8;

  short8 kr0, kr1, vr0, vr1;
  {
    kr0 = *(const short8*)(kg0);
    kr1 = *(const short8*)(kg1);
    vr0 = *(const short8*)(vg0);
    vr1 = *(const short8*)(vg1);
  }
  *(short8*)&Ks[p0 * 8] = kr0;
  *(short8*)&Ks[p1 * 8] = kr1;
  *(short8*)&Vs[p0 * 8] = vr0;
  *(short8*)&Vs[p1 * 8] = vr1;

  for (int it = 0; it < NIT; it++) {
    __syncthreads();   // staged LDS visible to all waves

    if (it + 1 < NIT) {
      const int kn = (it + 1) * 64;
      const size_t ko = (size_t)kn * D_MODEL;
      kr0 = *(const short8*)(kg0 + ko);
      kr1 = *(const short8*)(kg1 + ko);
      vr0 = *(const short8*)(vg0 + kn);
      vr1 = *(const short8*)(vg1 + kn);
    }

    // --- batched K-fragment reads for BOTH 32-key chunks (8 ds_read_b128)
    short8 af0[4], af1[4];
    #pragma unroll
    for (int es = 0; es < 4; es++) {
      af0[es] = *(const short8*)&Ks[(l31) * 64 + slotK[es]];
      af1[es] = *(const short8*)&Ks[(32 + l31) * 64 + slotK[es]];
    }

    // --- S^T both chunks: 8 MFMAs issued back-to-back
    f32x16 st0, st1;
    #pragma unroll
    for (int r = 0; r < 16; r++) { st0[r] = 0.f; st1[r] = 0.f; }
    __builtin_amdgcn_s_setprio(1);
    #pragma unroll
    for (int es = 0; es < 4; es++)
      st0 = __builtin_amdgcn_mfma_f32_32x32x16_bf16(af0[es], bq[es], st0,
                                                    0, 0, 0);
    #pragma unroll
    for (int es = 0; es < 4; es++)
      st1 = __builtin_amdgcn_mfma_f32_32x32x16_bf16(af1[es], bq[es], st1,
                                                    0, 0, 0);
    __builtin_amdgcn_s_setprio(0);

    // --- softmax chunk0 (exp2/pack overlaps chunk1's MFMAs in the pipe)
    short8 pb0[2], pb1[2];
    {
      #pragma unroll
      for (int r = 0; r < 16; r++) st0[r] = __builtin_amdgcn_exp2f(st0[r]);
      lsum += (((st0[0] + st0[1]) + (st0[2] + st0[3])) +
               ((st0[4] + st0[5]) + (st0[6] + st0[7]))) +
              (((st0[8] + st0[9]) + (st0[10] + st0[11])) +
               ((st0[12] + st0[13]) + (st0[14] + st0[15])));
      unsigned a0 = pk2(st0[0],  st0[1]),  b0 = pk2(st0[2],  st0[3]);
      unsigned c0 = pk2(st0[4],  st0[5]),  d0 = pk2(st0[6],  st0[7]);
      unsigned a1 = pk2(st0[8],  st0[9]),  b1 = pk2(st0[10], st0[11]);
      unsigned c1 = pk2(st0[12], st0[13]), d1 = pk2(st0[14], st0[15]);
      asm volatile("v_permlane32_swap_b32 %0, %1" : "+v"(a0), "+v"(c0));
      asm volatile("v_permlane32_swap_b32 %0, %1" : "+v"(b0), "+v"(d0));
      asm volatile("v_permlane32_swap_b32 %0, %1" : "+v"(a1), "+v"(c1));
      asm volatile("v_permlane32_swap_b32 %0, %1" : "+v"(b1), "+v"(d1));
      U4S8 u0; u0.u[0] = a0; u0.u[1] = b0; u0.u[2] = c0; u0.u[3] = d0;
      pb0[0] = u0.s;
      U4S8 u1; u1.u[0] = a1; u1.u[1] = b1; u1.u[2] = c1; u1.u[3] = d1;
      pb0[1] = u1.s;
    }
    // --- softmax chunk1
    {
      #pragma unroll
      for (int r = 0; r < 16; r++) st1[r] = __builtin_amdgcn_exp2f(st1[r]);
      lsum += (((st1[0] + st1[1]) + (st1[2] + st1[3])) +
               ((st1[4] + st1[5]) + (st1[6] + st1[7]))) +
              (((st1[8] + st1[9]) + (st1[10] + st1[11])) +
               ((st1[12] + st1[13]) + (st1[14] + st1[15])));
      unsigned a0 = pk2(st1[0],  st1[1]),  b0 = pk2(st1[2],  st1[3]);
      unsigned c0 = pk2(st1[4],  st1[5]),  d0 = pk2(st1[6],  st1[7]);
      unsigned a1 = pk2(st1[8],  st1[9]),  b1 = pk2(st1[10], st1[11]);
      unsigned c1 = pk2(st1[12], st1[13]), d1 = pk2(st1[14], st1[15]);
      asm volatile("v_permlane32_swap_b32 %0, %1" : "+v"(a0), "+v"(c0));
      asm volatile("v_permlane32_swap_b32 %0, %1" : "+v"(b0), "+v"(d0));
      asm volatile("v_permlane32_swap_b32 %0, %1" : "+v"(a1), "+v"(c1));
      asm volatile("v_permlane32_swap_b32 %0, %1" : "+v"(b1), "+v"(d1));
      U4S8 u0; u0.u[0] = a0; u0.u[1] = b0; u0.u[2] = c0; u0.u[3] = d0;
      pb1[0] = u0.s;
      U4S8 u1; u1.u[0] = a1; u1.u[1] = b1; u1.u[2] = c1; u1.u[3] = d1;
      pb1[1] = u1.s;
    }

    // --- PV both chunks (av reads then 16 MFMAs)
    {
      short8 av0[2][2], av1[2][2];
      #pragma unroll
      for (int et = 0; et < 2; et++)
        #pragma unroll
        for (int ks2 = 0; ks2 < 2; ks2++) {
          av0[et][ks2] =
              *(const short8*)&Vs[(et * 32 + l31) * 64 + slotV[0][ks2]];
          av1[et][ks2] =
              *(const short8*)&Vs[(et * 32 + l31) * 64 + slotV[1][ks2]];
        }
      __builtin_amdgcn_s_setprio(1);
      #pragma unroll
      for (int et = 0; et < 2; et++)
        #pragma unroll
        for (int ks2 = 0; ks2 < 2; ks2++)
          ot[et] = __builtin_amdgcn_mfma_f32_32x32x16_bf16(
              av0[et][ks2], pb0[ks2], ot[et], 0, 0, 0);
      #pragma unroll
      for (int et = 0; et < 2; et++)
        #pragma unroll
        for (int ks2 = 0; ks2 < 2; ks2++)
          ot[et] = __builtin_amdgcn_mfma_f32_32x32x16_bf16(
              av1[et][ks2], pb1[ks2], ot[et], 0, 0, 0);
      __builtin_amdgcn_s_setprio(0);
    }

    __syncthreads();   // all waves done reading Ks/Vs
    if (it + 1 < NIT) {
      *(short8*)&Ks[p0 * 8] = kr0;
      *(short8*)&Ks[p1 * 8] = kr1;
      *(short8*)&Vs[p0 * 8] = vr0;
      *(short8*)&Vs[p1 * 8] = vr1;
    }
  }

  // --- epilogue: normalize and write FINAL output directly to ocat
  // (layout [b][s][h*EHEAD+e]; reg r=rq*4+j -> e = et*32 + 8*rq + 4*hi + j)
  {
    const float s = lsum + __shfl_xor(lsum, 32);
    const float inv = 1.f / s;
    const int qL = q0 + qw + l31;
    ushort_t* orow = ocat + ((size_t)(b * SEQ + qL)) * D_MODEL + hc;
    #pragma unroll
    for (int et = 0; et < 2; et++)
      #pragma unroll
      for (int rq = 0; rq < 4; rq++) {
        const int e0 = et * 32 + rq * 8 + hi * 4;
        u64 pk = (u64)pk2(ot[et][rq * 4 + 0] * inv, ot[et][rq * 4 + 1] * inv) |
                 ((u64)pk2(ot[et][rq * 4 + 2] * inv, ot[et][rq * 4 + 3] * inv)
                  << 32);
        *(u64*)&orow[e0] = pk;
      }
  }
}

// ---------------------------------------------------------------------------
// 5 dispatches (R27 = R26 config + flash chunk-interleave):
//  0. cvt_pre  (H scaled + W^T transposed)
//  1. weff_cvt (mm64 Weff z<3) + z=3 cvt of E+WO (overlapped)
//  2. qkv_z  = E @ Weff_z^T       (mm128, 768 blk; z=2 operand-swapped)
//  3. flash NSPLIT=1              (R27: interleaved chunks, 512 blk)
//  4. out = ocat @ WO^T (fp32)    (mm64: 1024 blk, 4/CU)
// ws: 76.5 MB (R14 layout).
// ---------------------------------------------------------------------------
extern "C" void kernel_launch(void* const* d_in, const int* in_sizes, int n_in,
                              void* d_out, int out_size, void* d_ws, size_t ws_size,
                              hipStream_t stream) {
  const float* E  = (const float*)d_in[0];
  const float* WQ = (const float*)d_in[1];
  const float* WK = (const float*)d_in[2];
  const float* WV = (const float*)d_in[3];
  const float* WO = (const float*)d_in[4];
  const float* HQ = (const float*)d_in[5];
  const float* HK = (const float*)d_in[6];
  const float* HV = (const float*)d_in[7];
  float* out = (float*)d_out;

  const size_t NE = (size_t)BS_ROWS * D_MODEL;  // 4M
  const size_t NW = (size_t)D_MODEL * D_MODEL;  // 1M

  ushort_t* Ebf   = (ushort_t*)d_ws;            // 4M
  ushort_t* WOb   = Ebf + NE;                   // 1M
  ushort_t* Hb    = WOb + NW;                   // 3 x 1M
  ushort_t* Wt    = Hb + 3 * NW;                // 3 x 1M (W^T)
  ushort_t* Weff  = Wt + 3 * NW;                // 3 x 1M
  ushort_t* qb    = Weff + 3 * NW;              // 4M
  ushort_t* kb    = qb + NE;                    // 4M
  ushort_t* vTb   = kb + NE;                    // 4M ([b][he][s])
  ushort_t* ocat  = vTb + NE;                   // 4M

  // 0. cvt_pre: H (HQ scaled by 0.125*log2e) + W^T transposes
  {
    CvtPre a;
    const float* s2[6] = {HQ, HK, HV, WQ, WK, WV};
    ushort_t* dsts[6] = {Hb, Hb + NW, Hb + 2 * NW, Wt, Wt + NW, Wt + 2 * NW};
    for (int i = 0; i < 6; i++) {
      a.src[i] = s2[i]; a.dst[i] = dsts[i];
      a.scale[i] = (i == 0) ? (0.125f * 1.44269504088896f) : 1.0f;
    }
    cvt_pre<<<dim3(256, 6), 256, 0, stream>>>(a);
  }
  // 1. Weff_z = H_z @ W_z (z<3, mm64 body) + E/WO cvt (z=3, overlapped)
  {
    MM3 p;
    p.a[0] = Hb; p.a[1] = Hb + NW; p.a[2] = Hb + 2 * NW;
    p.b[0] = Wt; p.b[1] = Wt + NW; p.b[2] = Wt + 2 * NW;
    p.c[0] = Weff; p.c[1] = Weff + NW; p.c[2] = Weff + 2 * NW;
    weff_cvt<<<dim3(16, 16, 4), 256, 0, stream>>>(
        p, (const float4*)E, Ebf, (const float4*)WO, WOb);
  }
  // 2. qkv_z = E @ Weff_z^T  (z=2: A=Weff_v, B=Ebf -> vT direct)
  {
    MM3 p;
    p.a[0] = Ebf; p.a[1] = Ebf; p.a[2] = Weff + 2 * NW;
    p.b[0] = Weff; p.b[1] = Weff + NW; p.b[2] = Ebf;
    p.c[0] = qb; p.c[1] = kb; p.c[2] = vTb;
    mm128_bt<ushort_t><<<dim3(32, 8, 3), 256, 0, stream>>>(
        p, D_MODEL, D_MODEL, D_MODEL, D_MODEL);
  }
  // 3. flash NSPLIT=1 (16 x 32 = 512 blocks) -> ocat directly
  flash_attn<<<dim3(SEQ / QBLK, 32), 256, 0, stream>>>(qb, kb, vTb, ocat);
  // 4. out = ocat @ WO^T  (64-tile; 1024 blocks, 4/CU)
  {
    MM3 p;
    p.a[0] = ocat; p.b[0] = WOb; p.c[0] = out;
    p.a[1] = ocat; p.b[1] = WOb; p.c[1] = out;
    p.a[2] = ocat; p.b[2] = WOb; p.c[2] = out;
    mm64_bt<float><<<dim3(64, 16, 1), 256, 0, stream>>>(
        p, D_MODEL, D_MODEL, D_MODEL, D_MODEL);
  }
}